// Round 1
// baseline (242.731 us; speedup 1.0000x reference)
//
#include <hip/hip_runtime.h>
#include <cstdint>
#include <cstddef>

#define N_TOK 4096
#define CQ    256
#define CK    32

typedef __attribute__((ext_vector_type(4))) float  f32x4;
typedef __attribute__((ext_vector_type(8))) __bf16 bf16x8;

__device__ __forceinline__ unsigned short f2bf(float f) {
  union { float f; unsigned u; } x; x.f = f;
  unsigned r = x.u + 0x7FFFu + ((x.u >> 16) & 1u);   // RNE
  return (unsigned short)(r >> 16);
}

__device__ __forceinline__ f32x4 mfma16(bf16x8 a, bf16x8 b, f32x4 c) {
  return __builtin_amdgcn_mfma_f32_16x16x32_bf16(a, b, c, 0, 0, 0);
}

// ---------------------------------------------------------------------------
// K/V projection (contract dim = 32): K[b,n,o] bf16, VT[b,o,n] bf16
// block = 256 threads (thread = out-channel o), 32 tokens per block.
// ---------------------------------------------------------------------------
__global__ __launch_bounds__(256) void kvproj_kernel(
    const float* __restrict__ Xk, const float* __restrict__ Wk,
    const float* __restrict__ bk, const float* __restrict__ Wv,
    const float* __restrict__ bv, unsigned short* __restrict__ K,
    unsigned short* __restrict__ VT)
{
  __shared__ float xs[CK][32];
  __shared__ float vts[256][33];           // +1 pad: conflict-free column writes
  const int b  = blockIdx.x >> 7;
  const int n0 = (blockIdx.x & 127) << 5;
  const int t  = threadIdx.x;
  {
    int c = t >> 3, off = (t & 7) << 2;
    float4 v = *(const float4*)(Xk + ((size_t)b * CK + c) * N_TOK + n0 + off);
    xs[c][off] = v.x; xs[c][off+1] = v.y; xs[c][off+2] = v.z; xs[c][off+3] = v.w;
  }
  float wk[CK], wv[CK];
  #pragma unroll
  for (int c4 = 0; c4 < CK; c4 += 4) {
    float4 a = *(const float4*)(Wk + (size_t)t * CK + c4);
    wk[c4] = a.x; wk[c4+1] = a.y; wk[c4+2] = a.z; wk[c4+3] = a.w;
    float4 d = *(const float4*)(Wv + (size_t)t * CK + c4);
    wv[c4] = d.x; wv[c4+1] = d.y; wv[c4+2] = d.z; wv[c4+3] = d.w;
  }
  const float bko = bk[t], bvo = bv[t];
  __syncthreads();
  for (int nn = 0; nn < 32; nn++) {
    float ka = bko, va = bvo;
    #pragma unroll
    for (int c = 0; c < CK; c++) {
      float x = xs[c][nn];                 // broadcast read
      ka = fmaf(x, wk[c], ka);
      va = fmaf(x, wv[c], va);
    }
    K[((size_t)b * N_TOK + n0 + nn) * CQ + t] = f2bf(ka);   // coalesced
    vts[t][nn] = va;
  }
  __syncthreads();
  unsigned short tmp[32] __attribute__((aligned(16)));
  #pragma unroll
  for (int q = 0; q < 32; q++) tmp[q] = f2bf(vts[t][q]);
  unsigned short* dst = VT + ((size_t)b * CQ + t) * N_TOK + n0;
  #pragma unroll
  for (int i = 0; i < 4; i++) ((uint4*)dst)[i] = ((const uint4*)tmp)[i];
}

// ---------------------------------------------------------------------------
// Q projection (MFMA): QT[b,o,n] bf16 = (Wq @ X + bq) * SCALE
// grid 256: b(2) x mblock(4 of 64) x nblock(32 of 128). 4 waves, wave = 16 m-rows.
// ---------------------------------------------------------------------------
__global__ __launch_bounds__(256) void qproj_kernel(
    const float* __restrict__ X, const float* __restrict__ Wq,
    const float* __restrict__ bq, unsigned short* __restrict__ QT)
{
  __shared__ unsigned short bs[128][40];   // B^T tile [n][k], pad 32->40
  const int blk = blockIdx.x;
  const int b  = blk >> 7;
  const int mb = (blk >> 5) & 3;
  const int nb = blk & 31;
  const int m0 = mb << 6, n0 = nb << 7;
  const int t = threadIdx.x, w = t >> 6;
  const int lane = t & 63, c = lane & 15, g = lane >> 4;
  f32x4 acc[8] = {};
  for (int k0 = 0; k0 < CQ; k0 += 32) {
    #pragma unroll
    for (int i = 0; i < 4; i++) {          // stage X tile [32k][128n] -> bs[n][k]
      int q = t + (i << 8);
      int kk = q >> 5, nn = (q & 31) << 2;
      float4 v = *(const float4*)(X + ((size_t)b * CQ + k0 + kk) * N_TOK + n0 + nn);
      bs[nn  ][kk] = f2bf(v.x); bs[nn+1][kk] = f2bf(v.y);
      bs[nn+2][kk] = f2bf(v.z); bs[nn+3][kk] = f2bf(v.w);
    }
    __syncthreads();
    union { unsigned short s[8]; bf16x8 v; } au;   // A-frag direct from global Wq
    const float* ap = Wq + (size_t)(m0 + w * 16 + c) * CQ + k0 + g * 8;
    float4 a0 = *(const float4*)ap, a1 = *(const float4*)(ap + 4);
    au.s[0]=f2bf(a0.x); au.s[1]=f2bf(a0.y); au.s[2]=f2bf(a0.z); au.s[3]=f2bf(a0.w);
    au.s[4]=f2bf(a1.x); au.s[5]=f2bf(a1.y); au.s[6]=f2bf(a1.z); au.s[7]=f2bf(a1.w);
    #pragma unroll
    for (int nt = 0; nt < 8; nt++) {
      bf16x8 bf = *(const bf16x8*)&bs[nt * 16 + c][g * 8];
      acc[nt] = mfma16(au.v, bf, acc[nt]);
    }
    __syncthreads();
  }
  #pragma unroll
  for (int r = 0; r < 4; r++) {
    int m = m0 + w * 16 + g * 4 + r;
    float bias = bq[m];
    #pragma unroll
    for (int nt = 0; nt < 8; nt++)
      QT[((size_t)b * CQ + m) * N_TOK + n0 + nt * 16 + c] =
          f2bf((acc[nt][r] + bias) * 0.125f);    // fold attention SCALE here
  }
}

// ---------------------------------------------------------------------------
// Flash attention. 512 blocks x 128 thr (2 waves). Block = (b, qb of 64 q, key
// quarter). Wave = 32 queries (2 m-tiles). Emits unnormalized partial O + m,l.
// ---------------------------------------------------------------------------
__global__ __launch_bounds__(128, 1) void flash_kernel(
    const unsigned short* __restrict__ QT, const unsigned short* __restrict__ K,
    const unsigned short* __restrict__ VT, float* __restrict__ partO,
    float* __restrict__ partML)
{
  __shared__ unsigned short ks[32][264];   // K tile [key][d], pad 256->264
  __shared__ unsigned short vts[256][32];  // V^T tile [d][key]
  __shared__ unsigned short ps[2][16][40]; // per-wave P layout shuffle
  const int blk = blockIdx.x;              // = b*256 + qb*4 + ksp
  const int ksp = blk & 3;
  const int qb  = (blk >> 2) & 63;
  const int b   = blk >> 8;
  const int t = threadIdx.x, w = t >> 6;
  const int lane = t & 63, c = lane & 15, g = lane >> 4;
  const int q0 = qb * 64 + w * 32;

  bf16x8 qf[2][8];                         // Q A-frags, loaded once (scaled Q)
  #pragma unroll
  for (int mt = 0; mt < 2; mt++) {
    const unsigned short* qp = QT + (size_t)b * CQ * N_TOK + q0 + mt * 16 + c;
    #pragma unroll
    for (int ch = 0; ch < 8; ch++) {
      union { unsigned short s[8]; bf16x8 v; } u;
      #pragma unroll
      for (int j = 0; j < 8; j++)
        u.s[j] = qp[(size_t)(ch * 32 + g * 8 + j) * N_TOK];
      qf[mt][ch] = u.v;
    }
  }
  f32x4 o[2][16] = {};
  float m_i[2][4], l_i[2][4];
  #pragma unroll
  for (int mt = 0; mt < 2; mt++)
    #pragma unroll
    for (int r = 0; r < 4; r++) { m_i[mt][r] = -1e30f; l_i[mt][r] = 0.f; }

  const int kbase = ksp * 1024;
  for (int it = 0; it < 32; it++) {
    const int k0 = kbase + it * 32;
    const unsigned short* gK = K + ((size_t)b * N_TOK + k0) * CQ;  // contiguous 16KB
    #pragma unroll
    for (int r = 0; r < 8; r++) {
      int e = (r * 128 + t) * 8;
      uint4 v = *(const uint4*)(gK + e);
      *(uint4*)&ks[e >> 8][e & 255] = v;
    }
    #pragma unroll
    for (int r = 0; r < 8; r++) {
      int e = (r * 128 + t) * 8;
      int row = e >> 5, col = e & 31;
      uint4 v = *(const uint4*)(VT + ((size_t)b * CQ + row) * N_TOK + k0 + col);
      *(uint4*)&vts[row][col] = v;
    }
    __syncthreads();

    f32x4 s[2][2] = {};                    // S = Q K^T (scale pre-folded)
    #pragma unroll
    for (int nt = 0; nt < 2; nt++) {
      #pragma unroll
      for (int ch = 0; ch < 8; ch++) {
        bf16x8 bf = *(const bf16x8*)&ks[nt * 16 + c][ch * 32 + g * 8];
        s[0][nt] = mfma16(qf[0][ch], bf, s[0][nt]);
        s[1][nt] = mfma16(qf[1][ch], bf, s[1][nt]);
      }
    }

    float alpha[2][4];
    bf16x8 pf[2];
    #pragma unroll
    for (int mt = 0; mt < 2; mt++) {       // online softmax per m-tile
      float mx[4], rs[4];
      #pragma unroll
      for (int r = 0; r < 4; r++) mx[r] = fmaxf(s[mt][0][r], s[mt][1][r]);
      #pragma unroll
      for (int msk = 1; msk <= 8; msk <<= 1)
        #pragma unroll
        for (int r = 0; r < 4; r++) mx[r] = fmaxf(mx[r], __shfl_xor(mx[r], msk));
      #pragma unroll
      for (int r = 0; r < 4; r++) {
        float mn = fmaxf(m_i[mt][r], mx[r]);
        alpha[mt][r] = __expf(m_i[mt][r] - mn);
        m_i[mt][r] = mn;
        float p0 = __expf(s[mt][0][r] - mn);
        float p1 = __expf(s[mt][1][r] - mn);
        s[mt][0][r] = p0; s[mt][1][r] = p1;
        rs[r] = p0 + p1;
      }
      #pragma unroll
      for (int msk = 1; msk <= 8; msk <<= 1)
        #pragma unroll
        for (int r = 0; r < 4; r++) rs[r] += __shfl_xor(rs[r], msk);
      #pragma unroll
      for (int r = 0; r < 4; r++)
        l_i[mt][r] = l_i[mt][r] * alpha[mt][r] + rs[r];
      #pragma unroll
      for (int nt = 0; nt < 2; nt++)       // P: C-layout -> A-layout via LDS
        #pragma unroll
        for (int r = 0; r < 4; r++)
          ps[w][g * 4 + r][nt * 16 + c] = f2bf(s[mt][nt][r]);
      pf[mt] = *(const bf16x8*)&ps[w][c][g * 8];
    }

    float amin = 1.0f;                     // lazy O rescale
    #pragma unroll
    for (int mt = 0; mt < 2; mt++)
      #pragma unroll
      for (int r = 0; r < 4; r++) amin = fminf(amin, alpha[mt][r]);
    if (__any(amin < 1.0f)) {
      #pragma unroll
      for (int mt = 0; mt < 2; mt++)
        #pragma unroll
        for (int dt = 0; dt < 16; dt++)
          #pragma unroll
          for (int r = 0; r < 4; r++) o[mt][dt][r] *= alpha[mt][r];
    }

    #pragma unroll
    for (int dt = 0; dt < 16; dt++) {      // O += P V
      bf16x8 bv = *(const bf16x8*)&vts[dt * 16 + c][g * 8];
      o[0][dt] = mfma16(pf[0], bv, o[0][dt]);
      o[1][dt] = mfma16(pf[1], bv, o[1][dt]);
    }
    __syncthreads();
  }

  float* po = partO + ((size_t)blk * 2 + w) * (32 * 256);
  #pragma unroll
  for (int mt = 0; mt < 2; mt++)
    #pragma unroll
    for (int dt = 0; dt < 16; dt++)
      #pragma unroll
      for (int r = 0; r < 4; r++)
        po[(size_t)(mt * 16 + g * 4 + r) * 256 + dt * 16 + c] = o[mt][dt][r];
  if (c == 0) {
    float* pml = partML + ((size_t)blk * 2 + w) * 64;
    #pragma unroll
    for (int mt = 0; mt < 2; mt++)
      #pragma unroll
      for (int r = 0; r < 4; r++) {
        pml[mt * 16 + g * 4 + r]      = m_i[mt][r];
        pml[32 + mt * 16 + g * 4 + r] = l_i[mt][r];
      }
  }
}

// ---------------------------------------------------------------------------
// Merge 4 key-quarter partials -> OT[b,o,n] bf16 (normalized).
// 256 blocks (b x qb x wave), thread = d channel.
// ---------------------------------------------------------------------------
__global__ __launch_bounds__(256) void merge_kernel(
    const float* __restrict__ partO, const float* __restrict__ partML,
    unsigned short* __restrict__ OT)
{
  __shared__ float tr[256][33];
  const int blk = blockIdx.x;
  const int w  = blk & 1;
  const int qb = (blk >> 1) & 63;
  const int b  = blk >> 7;
  const int t  = threadIdx.x;
  const size_t base = (size_t)(b * 256 + qb * 4);    // flash blk base
  for (int q = 0; q < 32; q++) {
    float mv[4], lv[4], mmax = -1e30f;
    #pragma unroll
    for (int ksi = 0; ksi < 4; ksi++) {
      const float* pml = partML + ((base + ksi) * 2 + w) * 64;
      mv[ksi] = pml[q]; lv[ksi] = pml[32 + q];
      mmax = fmaxf(mmax, mv[ksi]);
    }
    float lsum = 0.f, f[4];
    #pragma unroll
    for (int ksi = 0; ksi < 4; ksi++) {
      f[ksi] = __expf(mv[ksi] - mmax);
      lsum = fmaf(f[ksi], lv[ksi], lsum);
    }
    float inv = 1.0f / lsum;
    float acc = 0.f;
    #pragma unroll
    for (int ksi = 0; ksi < 4; ksi++)
      acc = fmaf(f[ksi], partO[((base + ksi) * 2 + w) * 8192 + (size_t)q * 256 + t], acc);
    tr[t][q] = acc * inv;
  }
  __syncthreads();
  unsigned short tmp[32] __attribute__((aligned(16)));
  #pragma unroll
  for (int q = 0; q < 32; q++) tmp[q] = f2bf(tr[t][q]);
  unsigned short* dst = OT + ((size_t)b * CQ + t) * N_TOK + qb * 64 + w * 32;
  #pragma unroll
  for (int i = 0; i < 4; i++) ((uint4*)dst)[i] = ((const uint4*)tmp)[i];
}

// ---------------------------------------------------------------------------
// Output projection + residual (MFMA): Y[b,c,n] f32 = Wo @ OT + bo + X
// ---------------------------------------------------------------------------
__global__ __launch_bounds__(256) void oproj_kernel(
    const unsigned short* __restrict__ OT, const float* __restrict__ Wo,
    const float* __restrict__ bo, const float* __restrict__ X,
    float* __restrict__ Y)
{
  __shared__ unsigned short bs[128][40];
  const int blk = blockIdx.x;
  const int b  = blk >> 7;
  const int mb = (blk >> 5) & 3;
  const int nb = blk & 31;
  const int m0 = mb << 6, n0 = nb << 7;
  const int t = threadIdx.x, w = t >> 6;
  const int lane = t & 63, c = lane & 15, g = lane >> 4;
  f32x4 acc[8] = {};
  for (int k0 = 0; k0 < CQ; k0 += 32) {
    #pragma unroll
    for (int i = 0; i < 4; i++) {
      int q = t + (i << 8);
      int kk = q >> 5, nn = (q & 31) << 2;
      ushort4 v = *(const ushort4*)(OT + ((size_t)b * CQ + k0 + kk) * N_TOK + n0 + nn);
      bs[nn][kk] = v.x; bs[nn+1][kk] = v.y; bs[nn+2][kk] = v.z; bs[nn+3][kk] = v.w;
    }
    __syncthreads();
    union { unsigned short s[8]; bf16x8 v; } au;
    const float* ap = Wo + (size_t)(m0 + w * 16 + c) * CQ + k0 + g * 8;
    float4 a0 = *(const float4*)ap, a1 = *(const float4*)(ap + 4);
    au.s[0]=f2bf(a0.x); au.s[1]=f2bf(a0.y); au.s[2]=f2bf(a0.z); au.s[3]=f2bf(a0.w);
    au.s[4]=f2bf(a1.x); au.s[5]=f2bf(a1.y); au.s[6]=f2bf(a1.z); au.s[7]=f2bf(a1.w);
    #pragma unroll
    for (int nt = 0; nt < 8; nt++) {
      bf16x8 bf = *(const bf16x8*)&bs[nt * 16 + c][g * 8];
      acc[nt] = mfma16(au.v, bf, acc[nt]);
    }
    __syncthreads();
  }
  #pragma unroll
  for (int r = 0; r < 4; r++) {
    int m = m0 + w * 16 + g * 4 + r;
    float bias = bo[m];
    #pragma unroll
    for (int nt = 0; nt < 8; nt++) {
      size_t idx = ((size_t)b * CQ + m) * N_TOK + n0 + nt * 16 + c;
      Y[idx] = acc[nt][r] + bias + X[idx];
    }
  }
}

// ---------------------------------------------------------------------------
extern "C" void kernel_launch(void* const* d_in, const int* in_sizes, int n_in,
                              void* d_out, int out_size, void* d_ws, size_t ws_size,
                              hipStream_t stream) {
  const float* F  = (const float*)d_in[0];   // [2,256,4096]
  const float* Fk = (const float*)d_in[1];   // [2,32,4096]
  const float* Wq = (const float*)d_in[2];
  const float* bq = (const float*)d_in[3];
  const float* Wk = (const float*)d_in[4];
  const float* bk = (const float*)d_in[5];
  const float* Wv = (const float*)d_in[6];
  const float* bv = (const float*)d_in[7];
  const float* Wo = (const float*)d_in[8];
  const float* bo = (const float*)d_in[9];
  float* Y = (float*)d_out;
  char* ws = (char*)d_ws;
  unsigned short* QT = (unsigned short*)(ws);               // 4 MB  [2,256,4096] bf16
  unsigned short* K  = (unsigned short*)(ws + (4u  << 20)); // 4 MB  [2,4096,256] bf16
  unsigned short* VT = (unsigned short*)(ws + (8u  << 20)); // 4 MB  [2,256,4096] bf16
  unsigned short* OT = (unsigned short*)(ws + (12u << 20)); // 4 MB  [2,256,4096] bf16
  float* partO  = (float*)(ws + (16u << 20));               // 32 MB [512][2][32][256]
  float* partML = (float*)(ws + (48u << 20));               // 256 KB [512][2][2][32]

  kvproj_kernel<<<256, 256, 0, stream>>>(Fk, Wk, bk, Wv, bv, K, VT);
  qproj_kernel <<<256, 256, 0, stream>>>(F, Wq, bq, QT);
  flash_kernel <<<512, 128, 0, stream>>>(QT, K, VT, partO, partML);
  merge_kernel <<<256, 256, 0, stream>>>(partO, partML, OT);
  oproj_kernel <<<256, 256, 0, stream>>>(OT, Wo, bo, F, Y);
}

// Round 2
// 161.239 us; speedup vs baseline: 1.5054x; 1.5054x over previous
//
#include <hip/hip_runtime.h>
#include <cstdint>
#include <cstddef>

#define N_TOK 4096
#define CQ    256
#define CK    32
#define KSPLIT 16

typedef __attribute__((ext_vector_type(4))) float  f32x4;
typedef __attribute__((ext_vector_type(8))) __bf16 bf16x8;

__device__ __forceinline__ unsigned short f2bf(float f) {
  union { float f; unsigned u; } x; x.f = f;
  unsigned r = x.u + 0x7FFFu + ((x.u >> 16) & 1u);   // RNE
  return (unsigned short)(r >> 16);
}

__device__ __forceinline__ f32x4 mfma16(bf16x8 a, bf16x8 b, f32x4 c) {
  return __builtin_amdgcn_mfma_f32_16x16x32_bf16(a, b, c, 0, 0, 0);
}

// ---------------------------------------------------------------------------
// Weight fold. blocks 0..31: Aqkt[j][c] = SCALE * sum_i Wq[i,c]*Wk[i,j] (bf16)
//                            bqk[j]     = SCALE * sum_i bq[i]*Wk[i,j]   (f32)
// blocks 32..63: W2bf[o][j] = sum_i Wo[o,i]*Wv[i,j] (bf16)
//                c2[o]      = bo[o] + sum_i Wo[o,i]*bv[i]  (f32, block j==0)
// ---------------------------------------------------------------------------
__global__ __launch_bounds__(256) void fold_kernel(
    const float* __restrict__ Wq, const float* __restrict__ bq,
    const float* __restrict__ Wk, const float* __restrict__ Wv,
    const float* __restrict__ bv, const float* __restrict__ Wo,
    const float* __restrict__ bo, unsigned short* __restrict__ Aqkt,
    float* __restrict__ bqk, unsigned short* __restrict__ W2bf,
    float* __restrict__ c2)
{
  __shared__ float red[256];
  const int blk = blockIdx.x, t = threadIdx.x;
  if (blk < 32) {
    const int j = blk;
    float acc = 0.f;
    #pragma unroll 8
    for (int i = 0; i < CQ; i++)
      acc = fmaf(Wq[(size_t)i * CQ + t], Wk[(size_t)i * CK + j], acc);
    Aqkt[(size_t)j * CQ + t] = f2bf(0.125f * acc);
    red[t] = bq[t] * Wk[(size_t)t * CK + j];
    __syncthreads();
    for (int s = 128; s > 0; s >>= 1) {
      if (t < s) red[t] += red[t + s];
      __syncthreads();
    }
    if (t == 0) bqk[j] = 0.125f * red[0];
  } else {
    const int j = blk - 32;
    float acc = 0.f, acc2 = 0.f;
    #pragma unroll 8
    for (int i = 0; i < CQ; i++) {
      float wo = Wo[(size_t)t * CQ + i];
      acc  = fmaf(wo, Wv[(size_t)i * CK + j], acc);
      acc2 = fmaf(wo, bv[i], acc2);
    }
    W2bf[(size_t)t * CK + j] = f2bf(acc);
    if (j == 0) c2[t] = bo[t] + acc2;
  }
}

// ---------------------------------------------------------------------------
// xk prep: xkb[b][ch][tok] = bf16(Fk), XkT[b][tok][ch] = bf16(Fk) transposed.
// grid 64 (b x 32 token-tiles of 128), 256 thr.
// ---------------------------------------------------------------------------
__global__ __launch_bounds__(256) void xkprep_kernel(
    const float* __restrict__ Fk, unsigned short* __restrict__ xkb,
    unsigned short* __restrict__ XkT)
{
  __shared__ unsigned short trs[128][33];
  const int b = blockIdx.x >> 5;
  const int t0 = (blockIdx.x & 31) << 7;
  const int t = threadIdx.x;
  #pragma unroll
  for (int i = 0; i < 4; i++) {
    int flat = (i * 256 + t) << 2;            // over [32 ch][128 tok]
    int r = flat >> 7, c4 = flat & 127;
    float4 v = *(const float4*)(Fk + ((size_t)(b * CK + r)) * N_TOK + t0 + c4);
    ushort4 u = { f2bf(v.x), f2bf(v.y), f2bf(v.z), f2bf(v.w) };
    *(ushort4*)(xkb + ((size_t)(b * CK + r)) * N_TOK + t0 + c4) = u;
    trs[c4][r] = u.x; trs[c4+1][r] = u.y; trs[c4+2][r] = u.z; trs[c4+3][r] = u.w;
  }
  __syncthreads();
  const int token = t >> 1, half = t & 1;
  unsigned short tmp[16] __attribute__((aligned(16)));
  #pragma unroll
  for (int k = 0; k < 16; k++) tmp[k] = trs[token][half * 16 + k];
  unsigned short* dst = XkT + ((size_t)(b * N_TOK + t0 + token)) * CK + half * 16;
  ((uint4*)dst)[0] = ((const uint4*)tmp)[0];
  ((uint4*)dst)[1] = ((const uint4*)tmp)[1];
}

// ---------------------------------------------------------------------------
// Q'' projection: QN[b][tok][j=32] = bf16( xq . Aqk + bqk )  (SCALE folded)
// grid 256 (b x 128 token-tiles of 32), 128 thr = 2 waves (16 tokens each).
// ---------------------------------------------------------------------------
__global__ __launch_bounds__(128) void qproj_kernel(
    const float* __restrict__ X, const unsigned short* __restrict__ Aqkt,
    const float* __restrict__ bqk, unsigned short* __restrict__ QN)
{
  __shared__ unsigned short bs[32][40];
  const int b = blockIdx.x >> 7;
  const int t0 = (blockIdx.x & 127) << 5;
  const int t = threadIdx.x, w = t >> 6;
  const int lane = t & 63, c = lane & 15, g = lane >> 4;
  f32x4 acc[2] = {};
  for (int k0 = 0; k0 < CQ; k0 += 32) {
    #pragma unroll
    for (int i = 0; i < 2; i++) {            // stage X [32c][32tok] -> bs[tok][c]
      int flat = (i * 128 + t) << 2;
      int cc = flat >> 5, tk = flat & 31;
      float4 v = *(const float4*)(X + ((size_t)(b * CQ + k0 + cc)) * N_TOK + t0 + tk);
      bs[tk  ][cc] = f2bf(v.x); bs[tk+1][cc] = f2bf(v.y);
      bs[tk+2][cc] = f2bf(v.z); bs[tk+3][cc] = f2bf(v.w);
    }
    __syncthreads();
    bf16x8 a = *(const bf16x8*)&bs[w * 16 + c][g * 8];
    #pragma unroll
    for (int nt = 0; nt < 2; nt++) {
      bf16x8 bB = *(const bf16x8*)(Aqkt + (size_t)(nt * 16 + c) * CQ + k0 + g * 8);
      acc[nt] = mfma16(a, bB, acc[nt]);
    }
    __syncthreads();
  }
  #pragma unroll
  for (int nt = 0; nt < 2; nt++) {
    float bj = bqk[nt * 16 + c];
    #pragma unroll
    for (int r = 0; r < 4; r++)
      QN[((size_t)(b * N_TOK + t0 + w * 16 + g * 4 + r)) * CK + nt * 16 + c] =
          f2bf(acc[nt][r] + bj);
  }
}

// ---------------------------------------------------------------------------
// Flash attention, d=32. grid 1024 x 256 thr (4 indep waves). Wave = 32 q
// (2 m-tiles), ksplit=16 (256 keys / wave, 4 iters of 64). No block staging:
// A/B frags load straight from global; only per-wave P LDS round-trip.
// ---------------------------------------------------------------------------
__global__ __launch_bounds__(256) void flash_kernel(
    const unsigned short* __restrict__ QN, const unsigned short* __restrict__ XkT,
    const unsigned short* __restrict__ xkb, float* __restrict__ partO,
    float* __restrict__ partML)
{
  __shared__ unsigned short ps[4][16][72];   // per-wave, stride 144B (16B-mult)
  const int blk = blockIdx.x;
  const int b   = blk >> 9;
  const int qg  = (blk >> 4) & 31;
  const int ksp = blk & 15;
  const int t = threadIdx.x, w = t >> 6;
  const int lane = t & 63, c = lane & 15, g = lane >> 4;
  const int qtile = qg * 4 + w;
  const int q0 = qtile * 32;

  bf16x8 qf[2];
  #pragma unroll
  for (int mt = 0; mt < 2; mt++)
    qf[mt] = *(const bf16x8*)(QN + ((size_t)(b * N_TOK + q0 + mt * 16 + c)) * CK + g * 8);

  f32x4 o[2][2] = {};
  float m_i[2][4], l_i[2][4];
  #pragma unroll
  for (int mt = 0; mt < 2; mt++)
    #pragma unroll
    for (int r = 0; r < 4; r++) { m_i[mt][r] = -1e30f; l_i[mt][r] = 0.f; }

  for (int it = 0; it < 4; it++) {
    const int k0 = ksp * 256 + it * 64;
    // S = Q'' XkT^T  (contraction = 32 = one MFMA)
    f32x4 s[2][4] = {};
    #pragma unroll
    for (int nt = 0; nt < 4; nt++) {
      bf16x8 bk_ = *(const bf16x8*)(XkT + ((size_t)(b * N_TOK + k0 + nt * 16 + c)) * CK + g * 8);
      s[0][nt] = mfma16(qf[0], bk_, s[0][nt]);
      s[1][nt] = mfma16(qf[1], bk_, s[1][nt]);
    }
    // hoist PV B-frags (independent of softmax)
    bf16x8 bv_[2][2];
    #pragma unroll
    for (int dt = 0; dt < 2; dt++)
      #pragma unroll
      for (int kc = 0; kc < 2; kc++)
        bv_[dt][kc] = *(const bf16x8*)(xkb + ((size_t)(b * CK + dt * 16 + c)) * N_TOK + k0 + kc * 32 + g * 8);

    float alpha[2][4];
    bf16x8 pf[2][2];
    #pragma unroll
    for (int mt = 0; mt < 2; mt++) {
      float mx[4], rs[4];
      #pragma unroll
      for (int r = 0; r < 4; r++)
        mx[r] = fmaxf(fmaxf(s[mt][0][r], s[mt][1][r]), fmaxf(s[mt][2][r], s[mt][3][r]));
      #pragma unroll
      for (int msk = 1; msk <= 8; msk <<= 1)
        #pragma unroll
        for (int r = 0; r < 4; r++) mx[r] = fmaxf(mx[r], __shfl_xor(mx[r], msk));
      #pragma unroll
      for (int r = 0; r < 4; r++) {
        float mn = fmaxf(m_i[mt][r], mx[r]);
        alpha[mt][r] = __expf(m_i[mt][r] - mn);
        m_i[mt][r] = mn;
        rs[r] = 0.f;
        #pragma unroll
        for (int nt = 0; nt < 4; nt++) {
          float p = __expf(s[mt][nt][r] - mn);
          s[mt][nt][r] = p;
          rs[r] += p;
        }
      }
      #pragma unroll
      for (int msk = 1; msk <= 8; msk <<= 1)
        #pragma unroll
        for (int r = 0; r < 4; r++) rs[r] += __shfl_xor(rs[r], msk);
      #pragma unroll
      for (int r = 0; r < 4; r++)
        l_i[mt][r] = l_i[mt][r] * alpha[mt][r] + rs[r];
      #pragma unroll
      for (int nt = 0; nt < 4; nt++)       // P: C-layout -> A-layout (per-wave)
        #pragma unroll
        for (int r = 0; r < 4; r++)
          ps[w][g * 4 + r][nt * 16 + c] = f2bf(s[mt][nt][r]);
      pf[mt][0] = *(const bf16x8*)&ps[w][c][g * 8];
      pf[mt][1] = *(const bf16x8*)&ps[w][c][32 + g * 8];
    }
    #pragma unroll
    for (int mt = 0; mt < 2; mt++)
      #pragma unroll
      for (int dt = 0; dt < 2; dt++)
        #pragma unroll
        for (int r = 0; r < 4; r++) o[mt][dt][r] *= alpha[mt][r];
    #pragma unroll
    for (int mt = 0; mt < 2; mt++)
      #pragma unroll
      for (int dt = 0; dt < 2; dt++) {
        o[mt][dt] = mfma16(pf[mt][0], bv_[dt][0], o[mt][dt]);
        o[mt][dt] = mfma16(pf[mt][1], bv_[dt][1], o[mt][dt]);
      }
  }

  const int widx = (b * 128 + qtile) * KSPLIT + ksp;
  float* po = partO + (size_t)widx * 1024;
  #pragma unroll
  for (int mt = 0; mt < 2; mt++)
    #pragma unroll
    for (int dt = 0; dt < 2; dt++)
      #pragma unroll
      for (int r = 0; r < 4; r++)
        po[(size_t)(mt * 16 + g * 4 + r) * 32 + dt * 16 + c] = o[mt][dt][r];
  if (c == 0) {
    float* pml = partML + (size_t)widx * 64;
    #pragma unroll
    for (int mt = 0; mt < 2; mt++)
      #pragma unroll
      for (int r = 0; r < 4; r++) {
        pml[mt * 16 + g * 4 + r]      = m_i[mt][r];
        pml[32 + mt * 16 + g * 4 + r] = l_i[mt][r];
      }
  }
}

// ---------------------------------------------------------------------------
// Merge 16 key-split partials -> ON[b][tok][32] bf16 normalized.
// grid 128 x 256; thread = (q, d-quarter of 8).
// ---------------------------------------------------------------------------
__global__ __launch_bounds__(256) void merge_kernel(
    const float* __restrict__ partO, const float* __restrict__ partML,
    unsigned short* __restrict__ ON)
{
  const int gt = blockIdx.x * 256 + threadIdx.x;
  const int q  = gt >> 2, dq = gt & 3;
  const int b  = q >> 12;
  const int qq = q & 4095;
  const int qtile = qq >> 5, row = qq & 31;
  const int wbase = (b * 128 + qtile) * KSPLIT;
  float mv[KSPLIT], lv[KSPLIT], mmax = -1e30f;
  #pragma unroll
  for (int s = 0; s < KSPLIT; s++) {
    const float* pml = partML + (size_t)(wbase + s) * 64;
    mv[s] = pml[row]; lv[s] = pml[32 + row];
    mmax = fmaxf(mmax, mv[s]);
  }
  float lsum = 0.f, f[KSPLIT];
  #pragma unroll
  for (int s = 0; s < KSPLIT; s++) {
    f[s] = __expf(mv[s] - mmax);
    lsum = fmaf(f[s], lv[s], lsum);
  }
  const float inv = 1.0f / lsum;
  float acc[8] = {};
  #pragma unroll
  for (int s = 0; s < KSPLIT; s++) {
    const float* base = partO + (size_t)(wbase + s) * 1024 + row * 32 + dq * 8;
    float4 v0 = *(const float4*)(base);
    float4 v1 = *(const float4*)(base + 4);
    acc[0] = fmaf(f[s], v0.x, acc[0]); acc[1] = fmaf(f[s], v0.y, acc[1]);
    acc[2] = fmaf(f[s], v0.z, acc[2]); acc[3] = fmaf(f[s], v0.w, acc[3]);
    acc[4] = fmaf(f[s], v1.x, acc[4]); acc[5] = fmaf(f[s], v1.y, acc[5]);
    acc[6] = fmaf(f[s], v1.z, acc[6]); acc[7] = fmaf(f[s], v1.w, acc[7]);
  }
  unsigned short out8[8] __attribute__((aligned(16)));
  #pragma unroll
  for (int i = 0; i < 8; i++) out8[i] = f2bf(acc[i] * inv);
  *(uint4*)(ON + ((size_t)(b * N_TOK + qq)) * CK + dq * 8) = *(const uint4*)out8;
}

// ---------------------------------------------------------------------------
// Output projection + residual: Y[b][o][t] = ON . W2^T + c2 + X.
// grid 256 x 128 thr (2 waves of 16 o-rows); block = 32 o x 256 t.
// ---------------------------------------------------------------------------
__global__ __launch_bounds__(128) void oproj_kernel(
    const unsigned short* __restrict__ ON, const unsigned short* __restrict__ W2bf,
    const float* __restrict__ c2, const float* __restrict__ X,
    float* __restrict__ Y)
{
  const int blk = blockIdx.x;
  const int b  = blk >> 7;
  const int og = (blk >> 4) & 7;
  const int tt = blk & 15;
  const int t = threadIdx.x, w = t >> 6;
  const int lane = t & 63, c = lane & 15, g = lane >> 4;
  const int m0 = og * 32 + w * 16;
  const int t0 = tt * 256;
  bf16x8 aW = *(const bf16x8*)(W2bf + (size_t)(m0 + c) * CK + g * 8);
  f32x4 acc[16] = {};
  #pragma unroll
  for (int nt = 0; nt < 16; nt++) {
    bf16x8 bB = *(const bf16x8*)(ON + ((size_t)(b * N_TOK + t0 + nt * 16 + c)) * CK + g * 8);
    acc[nt] = mfma16(aW, bB, acc[nt]);
  }
  float cc2[4];
  #pragma unroll
  for (int r = 0; r < 4; r++) cc2[r] = c2[m0 + g * 4 + r];
  #pragma unroll
  for (int nt = 0; nt < 16; nt++)
    #pragma unroll
    for (int r = 0; r < 4; r++) {
      size_t idx = ((size_t)(b * CQ + m0 + g * 4 + r)) * N_TOK + t0 + nt * 16 + c;
      Y[idx] = acc[nt][r] + cc2[r] + X[idx];
    }
}

// ---------------------------------------------------------------------------
extern "C" void kernel_launch(void* const* d_in, const int* in_sizes, int n_in,
                              void* d_out, int out_size, void* d_ws, size_t ws_size,
                              hipStream_t stream) {
  const float* F  = (const float*)d_in[0];   // [2,256,4096]
  const float* Fk = (const float*)d_in[1];   // [2,32,4096]
  const float* Wq = (const float*)d_in[2];
  const float* bq = (const float*)d_in[3];
  const float* Wk = (const float*)d_in[4];
  // bk (d_in[5]) is provably softmax-invariant -> dropped
  const float* Wv = (const float*)d_in[6];
  const float* bv = (const float*)d_in[7];
  const float* Wo = (const float*)d_in[8];
  const float* bo = (const float*)d_in[9];
  float* Y = (float*)d_out;
  char* ws = (char*)d_ws;
  unsigned short* QN    = (unsigned short*)(ws);                 // 512 KB [2,4096,32]
  unsigned short* XkT   = (unsigned short*)(ws + (512u << 10));  // 512 KB [2,4096,32]
  unsigned short* xkb   = (unsigned short*)(ws + (1024u << 10)); // 512 KB [2,32,4096]
  unsigned short* ON    = (unsigned short*)(ws + (1536u << 10)); // 512 KB [2,4096,32]
  unsigned short* Aqkt  = (unsigned short*)(ws + (2048u << 10)); // 16 KB  [32,256]
  unsigned short* W2bf  = (unsigned short*)(ws + (2080u << 10)); // 16 KB  [256,32]
  float*          bqk   = (float*)(ws + (2112u << 10));          // 128 B
  float*          c2    = (float*)(ws + (2116u << 10));          // 1 KB
  float*          partML= (float*)(ws + (3072u << 10));          // 1 MB  [4096][64]
  float*          partO = (float*)(ws + (4096u << 10));          // 16 MB [4096][32][32]

  fold_kernel  <<<64,   256, 0, stream>>>(Wq, bq, Wk, Wv, bv, Wo, bo, Aqkt, bqk, W2bf, c2);
  xkprep_kernel<<<64,   256, 0, stream>>>(Fk, xkb, XkT);
  qproj_kernel <<<256,  128, 0, stream>>>(F, Aqkt, bqk, QN);
  flash_kernel <<<1024, 256, 0, stream>>>(QN, XkT, xkb, partO, partML);
  merge_kernel <<<128,  256, 0, stream>>>(partO, partML, ON);
  oproj_kernel <<<256,  128, 0, stream>>>(ON, W2bf, c2, F, Y);
}

// Round 3
// 157.099 us; speedup vs baseline: 1.5451x; 1.0263x over previous
//
#include <hip/hip_runtime.h>
#include <cstdint>
#include <cstddef>

#define N_TOK 4096
#define CQ    256
#define CK    32

typedef __attribute__((ext_vector_type(4))) float  f32x4;
typedef __attribute__((ext_vector_type(8))) __bf16 bf16x8;

__device__ __forceinline__ unsigned short f2bf(float f) {
  union { float f; unsigned u; } x; x.f = f;
  unsigned r = x.u + 0x7FFFu + ((x.u >> 16) & 1u);   // RNE
  return (unsigned short)(r >> 16);
}

__device__ __forceinline__ f32x4 mfma16(bf16x8 a, bf16x8 b, f32x4 c) {
  return __builtin_amdgcn_mfma_f32_16x16x32_bf16(a, b, c, 0, 0, 0);
}

// ---------------------------------------------------------------------------
// Prep: weight folds + xk bf16 prep, merged by blockIdx range. Grid 128 x 256.
//  blk 0..31  : Aqkt[j][c] = SCALE*sum_i Wq[i,c]*Wk[i,j]; bqk[j] (bk drops out
//               of softmax entirely - row-constant shift)
//  blk 32..63 : W2bf[o][j] = sum_i Wo[o,i]*Wv[i,j]; c2[o] = bo[o]+Wo.bv
//  blk 64..127: xkb[b][ch][tok] = bf16(Fk); XkT[b][tok][ch] = transpose
// ---------------------------------------------------------------------------
__global__ __launch_bounds__(256) void prep_kernel(
    const float* __restrict__ Wq, const float* __restrict__ bq,
    const float* __restrict__ Wk, const float* __restrict__ Wv,
    const float* __restrict__ bv, const float* __restrict__ Wo,
    const float* __restrict__ bo, const float* __restrict__ Fk,
    unsigned short* __restrict__ Aqkt, float* __restrict__ bqk,
    unsigned short* __restrict__ W2bf, float* __restrict__ c2,
    unsigned short* __restrict__ xkb, unsigned short* __restrict__ XkT)
{
  __shared__ float red[256];
  __shared__ unsigned short trs[128][33];
  const int blk = blockIdx.x, t = threadIdx.x;
  if (blk < 32) {
    const int j = blk;
    float acc = 0.f;
    #pragma unroll 8
    for (int i = 0; i < CQ; i++)
      acc = fmaf(Wq[(size_t)i * CQ + t], Wk[(size_t)i * CK + j], acc);
    Aqkt[(size_t)j * CQ + t] = f2bf(0.125f * acc);
    red[t] = bq[t] * Wk[(size_t)t * CK + j];
    __syncthreads();
    for (int s = 128; s > 0; s >>= 1) {
      if (t < s) red[t] += red[t + s];
      __syncthreads();
    }
    if (t == 0) bqk[j] = 0.125f * red[0];
  } else if (blk < 64) {
    const int j = blk - 32;
    float acc = 0.f, acc2 = 0.f;
    #pragma unroll 8
    for (int i = 0; i < CQ; i++) {
      float wo = Wo[(size_t)t * CQ + i];
      acc  = fmaf(wo, Wv[(size_t)i * CK + j], acc);
      acc2 = fmaf(wo, bv[i], acc2);
    }
    W2bf[(size_t)t * CK + j] = f2bf(acc);
    if (j == 0) c2[t] = bo[t] + acc2;
  } else {
    const int blk2 = blk - 64;
    const int b = blk2 >> 5;
    const int t0 = (blk2 & 31) << 7;
    #pragma unroll
    for (int i = 0; i < 4; i++) {
      int flat = (i * 256 + t) << 2;            // over [32 ch][128 tok]
      int r = flat >> 7, c4 = flat & 127;
      float4 v = *(const float4*)(Fk + ((size_t)(b * CK + r)) * N_TOK + t0 + c4);
      ushort4 u = { f2bf(v.x), f2bf(v.y), f2bf(v.z), f2bf(v.w) };
      *(ushort4*)(xkb + ((size_t)(b * CK + r)) * N_TOK + t0 + c4) = u;
      trs[c4][r] = u.x; trs[c4+1][r] = u.y; trs[c4+2][r] = u.z; trs[c4+3][r] = u.w;
    }
    __syncthreads();
    const int token = t >> 1, half = t & 1;
    unsigned short tmp[16] __attribute__((aligned(16)));
    #pragma unroll
    for (int k = 0; k < 16; k++) tmp[k] = trs[token][half * 16 + k];
    unsigned short* dst = XkT + ((size_t)(b * N_TOK + t0 + token)) * CK + half * 16;
    ((uint4*)dst)[0] = ((const uint4*)tmp)[0];
    ((uint4*)dst)[1] = ((const uint4*)tmp)[1];
  }
}

// ---------------------------------------------------------------------------
// Fused qproj + flash + in-LDS split-K merge. Grid 512 (b x 256 qtiles of 16
// tokens) x 256 thr (4 waves). Wave 0 computes the block's QN tile (16 MFMA
// from F + folded Aqk); every wave then handles 1024 keys (16 iters x 64),
// per-wave online softmax, and the 4 partials merge through LDS -> ON bf16.
// ---------------------------------------------------------------------------
__global__ __launch_bounds__(256) void flash_kernel(
    const float* __restrict__ F, const unsigned short* __restrict__ Aqkt,
    const float* __restrict__ bqk, const unsigned short* __restrict__ XkT,
    const unsigned short* __restrict__ xkb, unsigned short* __restrict__ ON)
{
  __shared__ unsigned short qn_s[16][40];   // QN tile [tok][j], row 80B (16B mult)
  __shared__ unsigned short ps[4][16][72];  // per-wave P transpose, row 144B
  __shared__ float om[4][16][32];           // per-wave O partial
  __shared__ float ml[4][2][16];            // per-wave m,l
  const int blk = blockIdx.x;
  const int b = blk >> 8;
  const int qtile = blk & 255;
  const int t0 = qtile * 16;
  const int t = threadIdx.x, w = t >> 6;
  const int lane = t & 63, c = lane & 15, g = lane >> 4;

  // ---- QN preamble (wave 0 only): QN = bf16(xq . Aqk + bqk) ----
  if (w == 0) {
    f32x4 qacc[2] = {};
    for (int k0 = 0; k0 < CQ; k0 += 32) {
      union { unsigned short s[8]; bf16x8 v; } au;   // A: xq[m=tok][k=ch]
      #pragma unroll
      for (int j = 0; j < 8; j++)
        au.s[j] = f2bf(F[((size_t)(b * CQ + k0 + g * 8 + j)) * N_TOK + t0 + c]);
      #pragma unroll
      for (int nt = 0; nt < 2; nt++) {
        bf16x8 bB = *(const bf16x8*)(Aqkt + (size_t)(nt * 16 + c) * CQ + k0 + g * 8);
        qacc[nt] = mfma16(au.v, bB, qacc[nt]);
      }
    }
    #pragma unroll
    for (int nt = 0; nt < 2; nt++) {
      float bj = bqk[nt * 16 + c];
      #pragma unroll
      for (int r = 0; r < 4; r++)
        qn_s[g * 4 + r][nt * 16 + c] = f2bf(qacc[nt][r] + bj);
    }
  }
  __syncthreads();
  const bf16x8 qf = *(const bf16x8*)&qn_s[c][g * 8];   // A-frag, k=32 -> 1 chunk

  f32x4 o[2] = {};
  float m_i[4], l_i[4];
  #pragma unroll
  for (int r = 0; r < 4; r++) { m_i[r] = -1e30f; l_i[r] = 0.f; }

  for (int it = 0; it < 16; it++) {
    const int k0 = w * 1024 + it * 64;
    f32x4 s[4] = {};                         // S rows=tok, cols=64 keys
    #pragma unroll
    for (int nt = 0; nt < 4; nt++) {
      bf16x8 bk_ = *(const bf16x8*)(XkT + ((size_t)(b * N_TOK + k0 + nt * 16 + c)) * CK + g * 8);
      s[nt] = mfma16(qf, bk_, s[nt]);
    }
    bf16x8 bv_[2][2];                        // PV B-frags (indep of softmax)
    #pragma unroll
    for (int dt = 0; dt < 2; dt++)
      #pragma unroll
      for (int kc = 0; kc < 2; kc++)
        bv_[dt][kc] = *(const bf16x8*)(xkb + ((size_t)(b * CK + dt * 16 + c)) * N_TOK + k0 + kc * 32 + g * 8);

    float mx[4], rs[4], alpha[4];
    #pragma unroll
    for (int r = 0; r < 4; r++)
      mx[r] = fmaxf(fmaxf(s[0][r], s[1][r]), fmaxf(s[2][r], s[3][r]));
    #pragma unroll
    for (int msk = 1; msk <= 8; msk <<= 1)
      #pragma unroll
      for (int r = 0; r < 4; r++) mx[r] = fmaxf(mx[r], __shfl_xor(mx[r], msk));
    #pragma unroll
    for (int r = 0; r < 4; r++) {
      float mn = fmaxf(m_i[r], mx[r]);
      alpha[r] = __expf(m_i[r] - mn);
      m_i[r] = mn;
      rs[r] = 0.f;
      #pragma unroll
      for (int nt = 0; nt < 4; nt++) {
        float p = __expf(s[nt][r] - mn);
        s[nt][r] = p;
        rs[r] += p;
      }
    }
    #pragma unroll
    for (int msk = 1; msk <= 8; msk <<= 1)
      #pragma unroll
      for (int r = 0; r < 4; r++) rs[r] += __shfl_xor(rs[r], msk);
    #pragma unroll
    for (int r = 0; r < 4; r++)
      l_i[r] = l_i[r] * alpha[r] + rs[r];
    #pragma unroll
    for (int nt = 0; nt < 4; nt++)           // P: C-layout -> A-layout (per-wave)
      #pragma unroll
      for (int r = 0; r < 4; r++)
        ps[w][g * 4 + r][nt * 16 + c] = f2bf(s[nt][r]);
    bf16x8 pf0 = *(const bf16x8*)&ps[w][c][g * 8];
    bf16x8 pf1 = *(const bf16x8*)&ps[w][c][32 + g * 8];
    #pragma unroll
    for (int dt = 0; dt < 2; dt++)
      #pragma unroll
      for (int r = 0; r < 4; r++) o[dt][r] *= alpha[r];
    #pragma unroll
    for (int dt = 0; dt < 2; dt++) {
      o[dt] = mfma16(pf0, bv_[dt][0], o[dt]);
      o[dt] = mfma16(pf1, bv_[dt][1], o[dt]);
    }
  }

  // ---- in-LDS merge of the 4 per-wave partials ----
  #pragma unroll
  for (int dt = 0; dt < 2; dt++)
    #pragma unroll
    for (int r = 0; r < 4; r++)
      om[w][g * 4 + r][dt * 16 + c] = o[dt][r];
  if (c == 0) {
    #pragma unroll
    for (int r = 0; r < 4; r++) {
      ml[w][0][g * 4 + r] = m_i[r];
      ml[w][1][g * 4 + r] = l_i[r];
    }
  }
  __syncthreads();
  if (t < 128) {
    const int row = t >> 3, c0 = (t & 7) * 4;
    float mM = -1e30f;
    #pragma unroll
    for (int w4 = 0; w4 < 4; w4++) mM = fmaxf(mM, ml[w4][0][row]);
    float lsum = 0.f, f[4];
    #pragma unroll
    for (int w4 = 0; w4 < 4; w4++) {
      f[w4] = __expf(ml[w4][0][row] - mM);
      lsum = fmaf(f[w4], ml[w4][1][row], lsum);
    }
    const float inv = 1.0f / lsum;
    float v[4] = {};
    #pragma unroll
    for (int w4 = 0; w4 < 4; w4++)
      #pragma unroll
      for (int i = 0; i < 4; i++)
        v[i] = fmaf(f[w4], om[w4][row][c0 + i], v[i]);
    ushort4 u = { f2bf(v[0] * inv), f2bf(v[1] * inv), f2bf(v[2] * inv), f2bf(v[3] * inv) };
    *(ushort4*)(ON + ((size_t)(b * N_TOK + t0 + row)) * CK + c0) = u;
  }
}

// ---------------------------------------------------------------------------
// Output projection + residual: Y[b][o][t] = ON . W2^T + c2 + X.
// Grid 128 (b x 4 og x 16 tt) x 256 thr (4 waves of 16 o-rows).
// ---------------------------------------------------------------------------
__global__ __launch_bounds__(256) void oproj_kernel(
    const unsigned short* __restrict__ ON, const unsigned short* __restrict__ W2bf,
    const float* __restrict__ c2, const float* __restrict__ X,
    float* __restrict__ Y)
{
  const int blk = blockIdx.x;
  const int b  = blk >> 6;
  const int og = (blk >> 4) & 3;
  const int tt = blk & 15;
  const int t = threadIdx.x, w = t >> 6;
  const int lane = t & 63, c = lane & 15, g = lane >> 4;
  const int m0 = og * 64 + w * 16;
  const int t0 = tt * 256;
  bf16x8 aW = *(const bf16x8*)(W2bf + (size_t)(m0 + c) * CK + g * 8);
  f32x4 acc[16] = {};
  #pragma unroll
  for (int nt = 0; nt < 16; nt++) {
    bf16x8 bB = *(const bf16x8*)(ON + ((size_t)(b * N_TOK + t0 + nt * 16 + c)) * CK + g * 8);
    acc[nt] = mfma16(aW, bB, acc[nt]);
  }
  float cc2[4];
  #pragma unroll
  for (int r = 0; r < 4; r++) cc2[r] = c2[m0 + g * 4 + r];
  #pragma unroll
  for (int nt = 0; nt < 16; nt++)
    #pragma unroll
    for (int r = 0; r < 4; r++) {
      size_t idx = ((size_t)(b * CQ + m0 + g * 4 + r)) * N_TOK + t0 + nt * 16 + c;
      Y[idx] = acc[nt][r] + cc2[r] + X[idx];
    }
}

// ---------------------------------------------------------------------------
extern "C" void kernel_launch(void* const* d_in, const int* in_sizes, int n_in,
                              void* d_out, int out_size, void* d_ws, size_t ws_size,
                              hipStream_t stream) {
  const float* F  = (const float*)d_in[0];   // [2,256,4096]
  const float* Fk = (const float*)d_in[1];   // [2,32,4096]
  const float* Wq = (const float*)d_in[2];
  const float* bq = (const float*)d_in[3];
  const float* Wk = (const float*)d_in[4];
  // bk (d_in[5]) is provably softmax-invariant -> dropped
  const float* Wv = (const float*)d_in[6];
  const float* bv = (const float*)d_in[7];
  const float* Wo = (const float*)d_in[8];
  const float* bo = (const float*)d_in[9];
  float* Y = (float*)d_out;
  char* ws = (char*)d_ws;
  unsigned short* XkT   = (unsigned short*)(ws);                 // 512 KB [2,4096,32]
  unsigned short* xkb   = (unsigned short*)(ws + (512u << 10));  // 512 KB [2,32,4096]
  unsigned short* ON    = (unsigned short*)(ws + (1024u << 10)); // 512 KB [2,4096,32]
  unsigned short* Aqkt  = (unsigned short*)(ws + (1536u << 10)); // 16 KB  [32,256]
  unsigned short* W2bf  = (unsigned short*)(ws + (1568u << 10)); // 16 KB  [256,32]
  float*          bqk   = (float*)(ws + (1600u << 10));          // 128 B
  float*          c2    = (float*)(ws + (1604u << 10));          // 1 KB

  prep_kernel <<<128, 256, 0, stream>>>(Wq, bq, Wk, Wv, bv, Wo, bo, Fk,
                                        Aqkt, bqk, W2bf, c2, xkb, XkT);
  flash_kernel<<<512, 256, 0, stream>>>(F, Aqkt, bqk, XkT, xkb, ON);
  oproj_kernel<<<128, 256, 0, stream>>>(ON, W2bf, c2, F, Y);
}